// Round 1
// baseline (1028.411 us; speedup 1.0000x reference)
//
#include <hip/hip_runtime.h>
#include <hip/hip_bf16.h>
#include <math.h>

#define EPSN 1e-12f

// ---------------- utility kernels ----------------

__global__ void zero_ints(int* p, int n) {
    int i = blockIdx.x * blockDim.x + threadIdx.x;
    if (i < n) p[i] = 0;
}

__global__ void init_out(float* out, const float* gb, int G) {
    int g = blockIdx.x * blockDim.x + threadIdx.x;
    if (g < G) out[g] = gb[0];
}

// v[c] = sum_j gather_w[j] * lin2_w[j][c]  (c<16);  v[16] = gather_w . lin2_b
__global__ void compute_v(const float* l2w, const float* l2b, const float* gw,
                          float* vbuf) {
    int t = threadIdx.x;
    if (t < 16) {
        float a = 0.f;
        for (int j = 0; j < 64; ++j) a = fmaf(gw[j], l2w[j * 16 + t], a);
        vbuf[t] = a;
    } else if (t == 16) {
        float a = 0.f;
        for (int j = 0; j < 64; ++j) a = fmaf(gw[j], l2b[j], a);
        vbuf[16] = a;
    }
}

// ---------------- lin1 + relu + row-normalize ----------------
// 16 lanes per node; lane c computes output component c.
__global__ void lin1_relu_norm(const float* __restrict__ x,
                               const float* __restrict__ W1,
                               const float* __restrict__ b1,
                               float* __restrict__ xn1, float* __restrict__ s1,
                               int N, int D) {
    __shared__ float Ws[16 * 75];
    __shared__ float Bs[16];
    for (int i = threadIdx.x; i < 16 * D; i += blockDim.x) Ws[i] = W1[i];
    if (threadIdx.x < 16) Bs[threadIdx.x] = b1[threadIdx.x];
    __syncthreads();

    int node = blockIdx.x * (blockDim.x >> 4) + (threadIdx.x >> 4);
    int c = threadIdx.x & 15;
    if (node >= N) return;

    const float* xr = x + (size_t)node * D;
    float acc = Bs[c];
    for (int k = 0; k < D; ++k) acc = fmaf(xr[k], Ws[c * D + k], acc);
    float h = fmaxf(acc, 0.f);

    float ss = h * h;
    ss += __shfl_xor(ss, 8);
    ss += __shfl_xor(ss, 4);
    ss += __shfl_xor(ss, 2);
    ss += __shfl_xor(ss, 1);
    float s = fmaxf(sqrtf(ss), EPSN);
    xn1[(size_t)node * 16 + c] = h / s;
    if (c == 0) s1[node] = s;
}

// ---------------- CSR build ----------------

__global__ void hist_dst(const int* __restrict__ dst, int E, int* __restrict__ deg) {
    int e = blockIdx.x * blockDim.x + threadIdx.x;
    if (e < E) atomicAdd(&deg[dst[e]], 1);
}

__global__ void scan_block(const int* __restrict__ deg, int* __restrict__ offs,
                           int* __restrict__ bsums, int N) {
    __shared__ int tmp[1024];
    int i = blockIdx.x * 1024 + threadIdx.x;
    int v = (i < N) ? deg[i] : 0;
    tmp[threadIdx.x] = v;
    __syncthreads();
    for (int off = 1; off < 1024; off <<= 1) {
        int t = (threadIdx.x >= off) ? tmp[threadIdx.x - off] : 0;
        __syncthreads();
        tmp[threadIdx.x] += t;
        __syncthreads();
    }
    if (i < N) offs[i] = tmp[threadIdx.x] - v;  // exclusive
    if (threadIdx.x == 1023) bsums[blockIdx.x] = tmp[1023];
}

__global__ void scan_bsums(int* bsums, int nb) {
    if (threadIdx.x == 0) {
        int run = 0;
        for (int i = 0; i < nb; ++i) {
            int t = bsums[i];
            bsums[i] = run;
            run += t;
        }
    }
}

__global__ void add_offs(int* __restrict__ offs, const int* __restrict__ bsums,
                         int* __restrict__ cursor, int N) {
    int i = blockIdx.x * blockDim.x + threadIdx.x;
    if (i < N) {
        int o = offs[i] + bsums[i >> 10];
        offs[i] = o;
        cursor[i] = o;
    }
}

__global__ void scatter_edges(const int* __restrict__ src, const int* __restrict__ dst,
                              int E, int* __restrict__ cursor,
                              int* __restrict__ csr_src) {
    int e = blockIdx.x * blockDim.x + threadIdx.x;
    if (e < E) {
        int d = dst[e];
        int pos = atomicAdd(&cursor[d], 1);
        csr_src[pos] = src[e];
    }
}

// ---------------- AGNN conv (dst-centric gather, fused softmax) ----------------
// VEC=true : payload = s1[n], out = [N,16] aggregated un-normalized features
// VEC=false: payload = p[n] (scalar projection), out = [N] scalar result
template <bool VEC>
__global__ void agnn_conv(const float* __restrict__ xn,
                          const float* __restrict__ payload,
                          const int* __restrict__ offs, const int* __restrict__ deg,
                          const int* __restrict__ csr_src,
                          const float* __restrict__ beta_p,
                          float* __restrict__ out, int N) {
    int node = blockIdx.x * (blockDim.x >> 4) + (threadIdx.x >> 4);
    int c = threadIdx.x & 15;
    if (node >= N) return;
    float beta = beta_p[0];
    float xd = xn[(size_t)node * 16 + c];

    // self edge (PyG AGNNConv adds self-loops)
    float d0 = xd * xd;
    d0 += __shfl_xor(d0, 8);
    d0 += __shfl_xor(d0, 4);
    d0 += __shfl_xor(d0, 2);
    d0 += __shfl_xor(d0, 1);
    float ex = expf(beta * d0);
    float denom = ex;
    float accv = 0.f, accs = 0.f;
    if (VEC)
        accv = ex * payload[node] * xd;
    else
        accs = ex * payload[node];

    int start = offs[node];
    int cnt = deg[node];
    for (int i = 0; i < cnt; ++i) {
        int j = csr_src[start + i];
        float xs = xn[(size_t)j * 16 + c];
        float d = xd * xs;
        d += __shfl_xor(d, 8);
        d += __shfl_xor(d, 4);
        d += __shfl_xor(d, 2);
        d += __shfl_xor(d, 1);
        float e = expf(beta * d);
        denom += e;
        if (VEC)
            accv = fmaf(e * payload[j], xs, accv);
        else
            accs = fmaf(e, payload[j], accs);
    }
    if (VEC)
        out[(size_t)node * 16 + c] = accv / denom;
    else if (c == 0)
        out[node] = accs / denom;
}

// ---------------- normalize conv1 output + scalar projection ----------------
__global__ void norm2_proj(const float* __restrict__ out1, const float* __restrict__ vbuf,
                           float* __restrict__ xn2, float* __restrict__ pbuf, int N) {
    int node = blockIdx.x * (blockDim.x >> 4) + (threadIdx.x >> 4);
    int c = threadIdx.x & 15;
    if (node >= N) return;
    float val = out1[(size_t)node * 16 + c];
    float ss = val * val;
    ss += __shfl_xor(ss, 8);
    ss += __shfl_xor(ss, 4);
    ss += __shfl_xor(ss, 2);
    ss += __shfl_xor(ss, 1);
    float s = fmaxf(sqrtf(ss), EPSN);
    xn2[(size_t)node * 16 + c] = val / s;
    float pv = val * vbuf[c];
    pv += __shfl_xor(pv, 8);
    pv += __shfl_xor(pv, 4);
    pv += __shfl_xor(pv, 2);
    pv += __shfl_xor(pv, 1);
    if (c == 0) pbuf[node] = pv;
}

// ---------------- pooling: out[g] += r[n] + c0 ----------------
__global__ void pool_kernel(const float* __restrict__ r, const int* __restrict__ batch,
                            const float* __restrict__ vbuf, float* __restrict__ out,
                            int N) {
    int i = blockIdx.x * blockDim.x + threadIdx.x;
    if (i < N) atomicAdd(&out[batch[i]], r[i] + vbuf[16]);
}

// ---------------- launcher ----------------

extern "C" void kernel_launch(void* const* d_in, const int* in_sizes, int n_in,
                              void* d_out, int out_size, void* d_ws, size_t ws_size,
                              hipStream_t stream) {
    const float* x = (const float*)d_in[0];
    const int* edge_index = (const int*)d_in[1];
    const int* batch = (const int*)d_in[2];
    const float* lin1_w = (const float*)d_in[4];
    const float* lin1_b = (const float*)d_in[5];
    const float* beta1 = (const float*)d_in[6];
    const float* beta2 = (const float*)d_in[7];
    const float* lin2_w = (const float*)d_in[8];
    const float* lin2_b = (const float*)d_in[9];
    const float* gather_w = (const float*)d_in[10];
    const float* gather_b = (const float*)d_in[11];
    float* out = (float*)d_out;

    const int N = in_sizes[2];
    const int E = in_sizes[1] / 2;
    const int D = in_sizes[0] / N;  // 75
    const int G = out_size;

    const int* src = edge_index;
    const int* dst = edge_index + E;

    // workspace carve (all 4-byte elems)
    float* w = (float*)d_ws;
    float* xn1 = w;              w += (size_t)N * 16;
    float* s1 = w;               w += N;
    float* out1 = w;             w += (size_t)N * 16;
    float* xn2 = w;              w += (size_t)N * 16;
    float* pbuf = w;             w += N;
    float* rbuf = w;             w += N;
    float* vbuf = w;             w += 32;
    int* deg = (int*)w;          w += N;
    int* offs = (int*)w;         w += N;
    int* cursor = (int*)w;       w += N;
    int* bsums = (int*)w;        w += 256;
    int* csr_src = (int*)w;      w += E;

    const int B = 256;
    const int nodesPerBlock = B / 16;  // 16
    dim3 gridNode16((N + nodesPerBlock - 1) / nodesPerBlock);
    dim3 gridN((N + B - 1) / B);
    dim3 gridE((E + B - 1) / B);
    int nb = (N + 1023) / 1024;

    // 1. lin1 + relu + normalize
    lin1_relu_norm<<<gridNode16, B, 0, stream>>>(x, lin1_w, lin1_b, xn1, s1, N, D);

    // 2. CSR build
    zero_ints<<<gridN, B, 0, stream>>>(deg, N);
    hist_dst<<<gridE, B, 0, stream>>>(dst, E, deg);
    scan_block<<<dim3(nb), 1024, 0, stream>>>(deg, offs, bsums, N);
    scan_bsums<<<dim3(1), 64, 0, stream>>>(bsums, nb);
    add_offs<<<gridN, B, 0, stream>>>(offs, bsums, cursor, N);
    scatter_edges<<<gridE, B, 0, stream>>>(src, dst, E, cursor, csr_src);

    // 3. epilogue projection vector
    compute_v<<<dim3(1), 64, 0, stream>>>(lin2_w, lin2_b, gather_w, vbuf);

    // 4. conv1 (vector aggregate)
    agnn_conv<true><<<gridNode16, B, 0, stream>>>(xn1, s1, offs, deg, csr_src,
                                                  beta1, out1, N);

    // 5. normalize + project
    norm2_proj<<<gridNode16, B, 0, stream>>>(out1, vbuf, xn2, pbuf, N);

    // 6. conv2 (scalar aggregate)
    agnn_conv<false><<<gridNode16, B, 0, stream>>>(xn2, pbuf, offs, deg, csr_src,
                                                   beta2, rbuf, N);

    // 7. pool + gather head
    init_out<<<dim3((G + B - 1) / B), B, 0, stream>>>(out, gather_b, G);
    pool_kernel<<<gridN, B, 0, stream>>>(rbuf, batch, vbuf, out, N);
}

// Round 2
// 617.056 us; speedup vs baseline: 1.6666x; 1.6666x over previous
//
#include <hip/hip_runtime.h>
#include <hip/hip_bf16.h>
#include <math.h>

#define EPSN 1e-12f
#define NPB 512           // nodes per bucket
#define NPB_SHIFT 9
#define SRC_BITS 17       // N = 131072 = 2^17
#define SRC_MASK ((1 << SRC_BITS) - 1)
#define MAXB 1024
#define A2_EPT 16         // edges per thread in bucket_scatter

// ---------------- utility kernels ----------------

__global__ void zero_ints(int* p, int n) {
    int i = blockIdx.x * blockDim.x + threadIdx.x;
    if (i < n) p[i] = 0;
}

__global__ void init_out(float* out, const float* gb, int G) {
    int g = blockIdx.x * blockDim.x + threadIdx.x;
    if (g < G) out[g] = gb[0];
}

// v[c] = sum_j gather_w[j] * lin2_w[j][c]  (c<16);  v[16] = gather_w . lin2_b
__global__ void compute_v(const float* l2w, const float* l2b, const float* gw,
                          float* vbuf) {
    int t = threadIdx.x;
    if (t < 16) {
        float a = 0.f;
        for (int j = 0; j < 64; ++j) a = fmaf(gw[j], l2w[j * 16 + t], a);
        vbuf[t] = a;
    } else if (t == 16) {
        float a = 0.f;
        for (int j = 0; j < 64; ++j) a = fmaf(gw[j], l2b[j], a);
        vbuf[16] = a;
    }
}

// ---------------- lin1 + relu + row-normalize ----------------
__global__ void lin1_relu_norm(const float* __restrict__ x,
                               const float* __restrict__ W1,
                               const float* __restrict__ b1,
                               float* __restrict__ xn1, float* __restrict__ s1,
                               int N, int D) {
    __shared__ float Ws[16 * 75];
    __shared__ float Bs[16];
    for (int i = threadIdx.x; i < 16 * D; i += blockDim.x) Ws[i] = W1[i];
    if (threadIdx.x < 16) Bs[threadIdx.x] = b1[threadIdx.x];
    __syncthreads();

    int node = blockIdx.x * (blockDim.x >> 4) + (threadIdx.x >> 4);
    int c = threadIdx.x & 15;
    if (node >= N) return;

    const float* xr = x + (size_t)node * D;
    float acc = Bs[c];
    for (int k = 0; k < D; ++k) acc = fmaf(xr[k], Ws[c * D + k], acc);
    float h = fmaxf(acc, 0.f);

    float ss = h * h;
    ss += __shfl_xor(ss, 8);
    ss += __shfl_xor(ss, 4);
    ss += __shfl_xor(ss, 2);
    ss += __shfl_xor(ss, 1);
    float s = fmaxf(sqrtf(ss), EPSN);
    xn1[(size_t)node * 16 + c] = h / s;
    if (c == 0) s1[node] = s;
}

// ---------------- bucketed CSR build ----------------

// Phase A1: per-bucket edge counts (LDS-aggregated histogram)
__global__ void bucket_count(const int* __restrict__ dst, int E,
                             int* __restrict__ gcount, int NB) {
    __shared__ int h[MAXB];
    for (int i = threadIdx.x; i < NB; i += blockDim.x) h[i] = 0;
    __syncthreads();
    for (int e = blockIdx.x * blockDim.x + threadIdx.x; e < E;
         e += gridDim.x * blockDim.x)
        atomicAdd(&h[dst[e] >> NPB_SHIFT], 1);
    __syncthreads();
    for (int i = threadIdx.x; i < NB; i += blockDim.x)
        if (h[i]) atomicAdd(&gcount[i], h[i]);
}

// scan bucket counts -> gbase (exclusive, NB+1) and init gcursor
__global__ void bucket_scan(const int* __restrict__ gcount, int* __restrict__ gbase,
                            int* __restrict__ gcursor, int NB) {
    __shared__ int tmp[MAXB];
    int t = threadIdx.x;
    int v = (t < NB) ? gcount[t] : 0;
    tmp[t] = v;
    __syncthreads();
    for (int off = 1; off < MAXB; off <<= 1) {
        int u = (t >= off) ? tmp[t - off] : 0;
        __syncthreads();
        tmp[t] += u;
        __syncthreads();
    }
    if (t < NB) {
        int ex = tmp[t] - v;
        gbase[t] = ex;
        gcursor[t] = ex;
    }
    if (t == NB - 1) gbase[NB] = tmp[t];
}

// Phase A2: scatter packed (dl<<17|src) into bucket-sorted order,
// block-aggregated rank so writes are ~16-edge consecutive runs per bucket.
__global__ void bucket_scatter(const int* __restrict__ src, const int* __restrict__ dst,
                               int E, int* __restrict__ gcursor,
                               int* __restrict__ packed, int NB) {
    __shared__ int h[MAXB];
    __shared__ int gpos[MAXB];
    for (int i = threadIdx.x; i < NB; i += blockDim.x) h[i] = 0;
    __syncthreads();
    int base = blockIdx.x * (blockDim.x * A2_EPT);
    int rs[A2_EPT], rd[A2_EPT], rr[A2_EPT];
#pragma unroll
    for (int k = 0; k < A2_EPT; ++k) {
        int e = base + k * blockDim.x + threadIdx.x;
        if (e < E) {
            rs[k] = src[e];
            rd[k] = dst[e];
            rr[k] = atomicAdd(&h[rd[k] >> NPB_SHIFT], 1);
        }
    }
    __syncthreads();
    for (int i = threadIdx.x; i < NB; i += blockDim.x) {
        int c = h[i];
        gpos[i] = c ? atomicAdd(&gcursor[i], c) : 0;
    }
    __syncthreads();
#pragma unroll
    for (int k = 0; k < A2_EPT; ++k) {
        int e = base + k * blockDim.x + threadIdx.x;
        if (e < E) {
            int b = rd[k] >> NPB_SHIFT;
            int dl = rd[k] & (NPB - 1);
            packed[gpos[b] + rr[k]] = (dl << SRC_BITS) | rs[k];
        }
    }
}

// Phase B: per-bucket local histogram + scan -> deg/offs/csr_src. 512 threads.
__global__ void csr_build(const int* __restrict__ packed, const int* __restrict__ gbase,
                          int* __restrict__ deg, int* __restrict__ offs,
                          int* __restrict__ csr_src, int N) {
    __shared__ int ldeg[NPB];
    __shared__ int lofs[NPB];
    int b = blockIdx.x;
    int t = threadIdx.x;
    int e0 = gbase[b], e1 = gbase[b + 1];
    int cnt = e1 - e0;
    ldeg[t] = 0;
    __syncthreads();
    for (int i = t; i < cnt; i += NPB)
        atomicAdd(&ldeg[packed[e0 + i] >> SRC_BITS], 1);
    __syncthreads();
    int v = ldeg[t];
    lofs[t] = v;
    __syncthreads();
    for (int off = 1; off < NPB; off <<= 1) {
        int u = (t >= off) ? lofs[t - off] : 0;
        __syncthreads();
        lofs[t] += u;
        __syncthreads();
    }
    int ex = lofs[t] - v;  // exclusive
    int node = (b << NPB_SHIFT) + t;
    if (node < N) {
        deg[node] = v;
        offs[node] = e0 + ex;
    }
    __syncthreads();
    lofs[t] = ex;  // reuse as cursor
    __syncthreads();
    for (int i = t; i < cnt; i += NPB) {
        int p = packed[e0 + i];
        int pos = atomicAdd(&lofs[p >> SRC_BITS], 1);
        csr_src[e0 + pos] = p & SRC_MASK;
    }
}

// ---------------- AGNN conv (dst-centric gather, fused softmax) ----------------
template <bool VEC>
__global__ void agnn_conv(const float* __restrict__ xn,
                          const float* __restrict__ payload,
                          const int* __restrict__ offs, const int* __restrict__ deg,
                          const int* __restrict__ csr_src,
                          const float* __restrict__ beta_p,
                          float* __restrict__ out, int N) {
    int node = blockIdx.x * (blockDim.x >> 4) + (threadIdx.x >> 4);
    int c = threadIdx.x & 15;
    if (node >= N) return;
    float beta = beta_p[0];
    float xd = xn[(size_t)node * 16 + c];

    // self edge (PyG AGNNConv adds self-loops)
    float d0 = xd * xd;
    d0 += __shfl_xor(d0, 8);
    d0 += __shfl_xor(d0, 4);
    d0 += __shfl_xor(d0, 2);
    d0 += __shfl_xor(d0, 1);
    float ex = __expf(beta * d0);
    float denom = ex;
    float accv = 0.f, accs = 0.f;
    if (VEC)
        accv = ex * payload[node] * xd;
    else
        accs = ex * payload[node];

    int start = offs[node];
    int cnt = deg[node];
    for (int i = 0; i < cnt; ++i) {
        int j = csr_src[start + i];
        float xs = xn[(size_t)j * 16 + c];
        float d = xd * xs;
        d += __shfl_xor(d, 8);
        d += __shfl_xor(d, 4);
        d += __shfl_xor(d, 2);
        d += __shfl_xor(d, 1);
        float e = __expf(beta * d);
        denom += e;
        if (VEC)
            accv = fmaf(e * payload[j], xs, accv);
        else
            accs = fmaf(e, payload[j], accs);
    }
    if (VEC)
        out[(size_t)node * 16 + c] = accv / denom;
    else if (c == 0)
        out[node] = accs / denom;
}

// ---------------- normalize conv1 output + scalar projection ----------------
__global__ void norm2_proj(const float* __restrict__ out1, const float* __restrict__ vbuf,
                           float* __restrict__ xn2, float* __restrict__ pbuf, int N) {
    int node = blockIdx.x * (blockDim.x >> 4) + (threadIdx.x >> 4);
    int c = threadIdx.x & 15;
    if (node >= N) return;
    float val = out1[(size_t)node * 16 + c];
    float ss = val * val;
    ss += __shfl_xor(ss, 8);
    ss += __shfl_xor(ss, 4);
    ss += __shfl_xor(ss, 2);
    ss += __shfl_xor(ss, 1);
    float s = fmaxf(sqrtf(ss), EPSN);
    xn2[(size_t)node * 16 + c] = val / s;
    float pv = val * vbuf[c];
    pv += __shfl_xor(pv, 8);
    pv += __shfl_xor(pv, 4);
    pv += __shfl_xor(pv, 2);
    pv += __shfl_xor(pv, 1);
    if (c == 0) pbuf[node] = pv;
}

// ---------------- pooling: out[g] += r[n] + c0 ----------------
__global__ void pool_kernel(const float* __restrict__ r, const int* __restrict__ batch,
                            const float* __restrict__ vbuf, float* __restrict__ out,
                            int N) {
    int i = blockIdx.x * blockDim.x + threadIdx.x;
    if (i < N) atomicAdd(&out[batch[i]], r[i] + vbuf[16]);
}

// ---------------- launcher ----------------

extern "C" void kernel_launch(void* const* d_in, const int* in_sizes, int n_in,
                              void* d_out, int out_size, void* d_ws, size_t ws_size,
                              hipStream_t stream) {
    const float* x = (const float*)d_in[0];
    const int* edge_index = (const int*)d_in[1];
    const int* batch = (const int*)d_in[2];
    const float* lin1_w = (const float*)d_in[4];
    const float* lin1_b = (const float*)d_in[5];
    const float* beta1 = (const float*)d_in[6];
    const float* beta2 = (const float*)d_in[7];
    const float* lin2_w = (const float*)d_in[8];
    const float* lin2_b = (const float*)d_in[9];
    const float* gather_w = (const float*)d_in[10];
    const float* gather_b = (const float*)d_in[11];
    float* out = (float*)d_out;

    const int N = in_sizes[2];
    const int E = in_sizes[1] / 2;
    const int D = in_sizes[0] / N;  // 75
    const int G = out_size;
    const int NB = (N + NPB - 1) >> NPB_SHIFT;  // 256 buckets

    const int* src = edge_index;
    const int* dst = edge_index + E;

    // workspace carve (all 4-byte elems)
    // Float region (51N+32) is written only AFTER the CSR build, so the
    // packed edge buffer (E ints) aliases it.
    float* w = (float*)d_ws;
    int* packed = (int*)d_ws;    // E ints, aliases float region below
    float* xn1 = w;              w += (size_t)N * 16;
    float* s1 = w;               w += N;
    float* out1 = w;             w += (size_t)N * 16;
    float* xn2 = w;              w += (size_t)N * 16;
    float* pbuf = w;             w += N;
    float* rbuf = w;             w += N;
    float* vbuf = w;             w += 32;
    int* deg = (int*)w;          w += N;
    int* offs = (int*)w;         w += N;
    int* csr_src = (int*)w;      w += E;
    int* gcount = (int*)w;       w += MAXB;
    int* gbase = (int*)w;        w += MAXB + 1;
    int* gcursor = (int*)w;      w += MAXB;

    const int B = 256;
    const int nodesPerBlock = B / 16;  // 16
    dim3 gridNode16((N + nodesPerBlock - 1) / nodesPerBlock);
    dim3 gridN((N + B - 1) / B);

    // ---- CSR build (before anything touches the float region) ----
    zero_ints<<<dim3((MAXB + B - 1) / B), B, 0, stream>>>(gcount, MAXB);
    bucket_count<<<dim3(1024), B, 0, stream>>>(dst, E, gcount, NB);
    bucket_scan<<<dim3(1), MAXB, 0, stream>>>(gcount, gbase, gcursor, NB);
    bucket_scatter<<<dim3((E + B * A2_EPT - 1) / (B * A2_EPT)), B, 0, stream>>>(
        src, dst, E, gcursor, packed, NB);
    csr_build<<<dim3(NB), NPB, 0, stream>>>(packed, gbase, deg, offs, csr_src, N);

    // ---- features ----
    lin1_relu_norm<<<gridNode16, B, 0, stream>>>(x, lin1_w, lin1_b, xn1, s1, N, D);
    compute_v<<<dim3(1), 64, 0, stream>>>(lin2_w, lin2_b, gather_w, vbuf);

    agnn_conv<true><<<gridNode16, B, 0, stream>>>(xn1, s1, offs, deg, csr_src,
                                                  beta1, out1, N);
    norm2_proj<<<gridNode16, B, 0, stream>>>(out1, vbuf, xn2, pbuf, N);
    agnn_conv<false><<<gridNode16, B, 0, stream>>>(xn2, pbuf, offs, deg, csr_src,
                                                   beta2, rbuf, N);

    init_out<<<dim3((G + B - 1) / B), B, 0, stream>>>(out, gather_b, G);
    pool_kernel<<<gridN, B, 0, stream>>>(rbuf, batch, vbuf, out, N);
}

// Round 3
// 452.636 us; speedup vs baseline: 2.2720x; 1.3632x over previous
//
#include <hip/hip_runtime.h>
#include <hip/hip_bf16.h>
#include <hip/hip_fp16.h>
#include <math.h>

#define EPSN 1e-12f
#define NPB 512           // nodes per bucket
#define NPB_SHIFT 9
#define SRC_BITS 17       // N = 131072 = 2^17
#define SRC_MASK ((1 << SRC_BITS) - 1)
#define MAXB 1024
#define A2_EPT 16         // edges per thread in bucket_scatter

// ---------------- utility kernels ----------------

__global__ void zero_ints(int* p, int n) {
    int i = blockIdx.x * blockDim.x + threadIdx.x;
    if (i < n) p[i] = 0;
}

__global__ void init_out(float* out, const float* gb, int G) {
    int g = blockIdx.x * blockDim.x + threadIdx.x;
    if (g < G) out[g] = gb[0];
}

// v[c] = sum_j gather_w[j] * lin2_w[j][c]  (c<16);  v[16] = gather_w . lin2_b
__global__ void compute_v(const float* l2w, const float* l2b, const float* gw,
                          float* vbuf) {
    int t = threadIdx.x;
    if (t < 16) {
        float a = 0.f;
        for (int j = 0; j < 64; ++j) a = fmaf(gw[j], l2w[j * 16 + t], a);
        vbuf[t] = a;
    } else if (t == 16) {
        float a = 0.f;
        for (int j = 0; j < 64; ++j) a = fmaf(gw[j], l2b[j], a);
        vbuf[16] = a;
    }
}

// ---------------- lin1 + relu + row-normalize (fp16 xn output) ----------------
__global__ void lin1_relu_norm(const float* __restrict__ x,
                               const float* __restrict__ W1,
                               const float* __restrict__ b1,
                               __half* __restrict__ xn1h, float* __restrict__ s1,
                               int N, int D) {
    __shared__ float Ws[16 * 75];
    __shared__ float Bs[16];
    for (int i = threadIdx.x; i < 16 * D; i += blockDim.x) Ws[i] = W1[i];
    if (threadIdx.x < 16) Bs[threadIdx.x] = b1[threadIdx.x];
    __syncthreads();

    int node = blockIdx.x * (blockDim.x >> 4) + (threadIdx.x >> 4);
    int c = threadIdx.x & 15;
    if (node >= N) return;

    const float* xr = x + (size_t)node * D;
    float acc = Bs[c];
    for (int k = 0; k < D; ++k) acc = fmaf(xr[k], Ws[c * D + k], acc);
    float h = fmaxf(acc, 0.f);

    float ss = h * h;
    ss += __shfl_xor(ss, 8);
    ss += __shfl_xor(ss, 4);
    ss += __shfl_xor(ss, 2);
    ss += __shfl_xor(ss, 1);
    float s = fmaxf(sqrtf(ss), EPSN);
    xn1h[(size_t)node * 16 + c] = __float2half_rn(h / s);
    if (c == 0) s1[node] = s;
}

// ---------------- bucketed CSR build ----------------

__global__ void bucket_count(const int* __restrict__ dst, int E,
                             int* __restrict__ gcount, int NB) {
    __shared__ int h[MAXB];
    for (int i = threadIdx.x; i < NB; i += blockDim.x) h[i] = 0;
    __syncthreads();
    for (int e = blockIdx.x * blockDim.x + threadIdx.x; e < E;
         e += gridDim.x * blockDim.x)
        atomicAdd(&h[dst[e] >> NPB_SHIFT], 1);
    __syncthreads();
    for (int i = threadIdx.x; i < NB; i += blockDim.x)
        if (h[i]) atomicAdd(&gcount[i], h[i]);
}

__global__ void bucket_scan(const int* __restrict__ gcount, int* __restrict__ gbase,
                            int* __restrict__ gcursor, int NB) {
    __shared__ int tmp[MAXB];
    int t = threadIdx.x;
    int v = (t < NB) ? gcount[t] : 0;
    tmp[t] = v;
    __syncthreads();
    for (int off = 1; off < MAXB; off <<= 1) {
        int u = (t >= off) ? tmp[t - off] : 0;
        __syncthreads();
        tmp[t] += u;
        __syncthreads();
    }
    if (t < NB) {
        int ex = tmp[t] - v;
        gbase[t] = ex;
        gcursor[t] = ex;
    }
    if (t == NB - 1) gbase[NB] = tmp[t];
}

__global__ void bucket_scatter(const int* __restrict__ src, const int* __restrict__ dst,
                               int E, int* __restrict__ gcursor,
                               int* __restrict__ packed, int NB) {
    __shared__ int h[MAXB];
    __shared__ int gpos[MAXB];
    for (int i = threadIdx.x; i < NB; i += blockDim.x) h[i] = 0;
    __syncthreads();
    int base = blockIdx.x * (blockDim.x * A2_EPT);
    int rs[A2_EPT], rd[A2_EPT], rr[A2_EPT];
#pragma unroll
    for (int k = 0; k < A2_EPT; ++k) {
        int e = base + k * blockDim.x + threadIdx.x;
        if (e < E) {
            rs[k] = src[e];
            rd[k] = dst[e];
            rr[k] = atomicAdd(&h[rd[k] >> NPB_SHIFT], 1);
        }
    }
    __syncthreads();
    for (int i = threadIdx.x; i < NB; i += blockDim.x) {
        int c = h[i];
        gpos[i] = c ? atomicAdd(&gcursor[i], c) : 0;
    }
    __syncthreads();
#pragma unroll
    for (int k = 0; k < A2_EPT; ++k) {
        int e = base + k * blockDim.x + threadIdx.x;
        if (e < E) {
            int b = rd[k] >> NPB_SHIFT;
            int dl = rd[k] & (NPB - 1);
            packed[gpos[b] + rr[k]] = (dl << SRC_BITS) | rs[k];
        }
    }
}

__global__ void csr_build(const int* __restrict__ packed, const int* __restrict__ gbase,
                          int* __restrict__ deg, int* __restrict__ offs,
                          int* __restrict__ csr_src, int N) {
    __shared__ int ldeg[NPB];
    __shared__ int lofs[NPB];
    int b = blockIdx.x;
    int t = threadIdx.x;
    int e0 = gbase[b], e1 = gbase[b + 1];
    int cnt = e1 - e0;
    ldeg[t] = 0;
    __syncthreads();
    for (int i = t; i < cnt; i += NPB)
        atomicAdd(&ldeg[packed[e0 + i] >> SRC_BITS], 1);
    __syncthreads();
    int v = ldeg[t];
    lofs[t] = v;
    __syncthreads();
    for (int off = 1; off < NPB; off <<= 1) {
        int u = (t >= off) ? lofs[t - off] : 0;
        __syncthreads();
        lofs[t] += u;
        __syncthreads();
    }
    int ex = lofs[t] - v;  // exclusive
    int node = (b << NPB_SHIFT) + t;
    if (node < N) {
        deg[node] = v;
        offs[node] = e0 + ex;
    }
    __syncthreads();
    lofs[t] = ex;  // reuse as cursor
    __syncthreads();
    for (int i = t; i < cnt; i += NPB) {
        int p = packed[e0 + i];
        int pos = atomicAdd(&lofs[p >> SRC_BITS], 1);
        csr_src[e0 + pos] = p & SRC_MASK;
    }
}

// ---------------- AGNN conv: 8 lanes/node, fp16 table, unroll-2 ----------------
template <bool VEC>
__global__ void agnn_conv(const __half* __restrict__ xnh,
                          const float* __restrict__ payload,
                          const int* __restrict__ offs, const int* __restrict__ deg,
                          const int* __restrict__ csr_src,
                          const float* __restrict__ beta_p,
                          float* __restrict__ out, int N) {
    int node = blockIdx.x * (blockDim.x >> 3) + (threadIdx.x >> 3);
    int c2 = threadIdx.x & 7;
    if (node >= N) return;
    float beta = beta_p[0];

    float2 xd = __half22float2(((const __half2*)(xnh + (size_t)node * 16))[c2]);

    // self edge (PyG AGNNConv adds self-loops)
    float d0 = fmaf(xd.x, xd.x, xd.y * xd.y);
    d0 += __shfl_xor(d0, 4);
    d0 += __shfl_xor(d0, 2);
    d0 += __shfl_xor(d0, 1);
    float ex = __expf(beta * d0);
    float denom = ex;
    float pself = payload[node];
    float2 accv = make_float2(0.f, 0.f);
    float accs = 0.f;
    if (VEC) {
        accv.x = ex * pself * xd.x;
        accv.y = ex * pself * xd.y;
    } else {
        accs = ex * pself;
    }

    int start = offs[node];
    int cnt = deg[node];
    int i = 0;
    for (; i + 2 <= cnt; i += 2) {
        int j0 = csr_src[start + i];
        int j1 = csr_src[start + i + 1];
        float2 xs0 = __half22float2(((const __half2*)(xnh + (size_t)j0 * 16))[c2]);
        float2 xs1 = __half22float2(((const __half2*)(xnh + (size_t)j1 * 16))[c2]);
        float p0 = payload[j0];
        float p1 = payload[j1];
        float da = fmaf(xd.x, xs0.x, xd.y * xs0.y);
        float db = fmaf(xd.x, xs1.x, xd.y * xs1.y);
        da += __shfl_xor(da, 4);
        da += __shfl_xor(da, 2);
        da += __shfl_xor(da, 1);
        db += __shfl_xor(db, 4);
        db += __shfl_xor(db, 2);
        db += __shfl_xor(db, 1);
        float e0 = __expf(beta * da);
        float e1 = __expf(beta * db);
        denom += e0 + e1;
        if (VEC) {
            float w0 = e0 * p0, w1 = e1 * p1;
            accv.x = fmaf(w0, xs0.x, accv.x);
            accv.y = fmaf(w0, xs0.y, accv.y);
            accv.x = fmaf(w1, xs1.x, accv.x);
            accv.y = fmaf(w1, xs1.y, accv.y);
        } else {
            accs = fmaf(e0, p0, accs);
            accs = fmaf(e1, p1, accs);
        }
    }
    if (i < cnt) {
        int j = csr_src[start + i];
        float2 xs = __half22float2(((const __half2*)(xnh + (size_t)j * 16))[c2]);
        float p = payload[j];
        float d = fmaf(xd.x, xs.x, xd.y * xs.y);
        d += __shfl_xor(d, 4);
        d += __shfl_xor(d, 2);
        d += __shfl_xor(d, 1);
        float e = __expf(beta * d);
        denom += e;
        if (VEC) {
            float w = e * p;
            accv.x = fmaf(w, xs.x, accv.x);
            accv.y = fmaf(w, xs.y, accv.y);
        } else {
            accs = fmaf(e, p, accs);
        }
    }

    float inv = 1.f / denom;
    if (VEC) {
        ((float2*)(out + (size_t)node * 16))[c2] = make_float2(accv.x * inv, accv.y * inv);
    } else if (c2 == 0) {
        out[node] = accs * inv;
    }
}

// ---------------- normalize conv1 output + scalar projection ----------------
__global__ void norm2_proj(const float* __restrict__ out1, const float* __restrict__ vbuf,
                           __half* __restrict__ xn2h, float* __restrict__ pbuf, int N) {
    int node = blockIdx.x * (blockDim.x >> 4) + (threadIdx.x >> 4);
    int c = threadIdx.x & 15;
    if (node >= N) return;
    float val = out1[(size_t)node * 16 + c];
    float ss = val * val;
    ss += __shfl_xor(ss, 8);
    ss += __shfl_xor(ss, 4);
    ss += __shfl_xor(ss, 2);
    ss += __shfl_xor(ss, 1);
    float s = fmaxf(sqrtf(ss), EPSN);
    xn2h[(size_t)node * 16 + c] = __float2half_rn(val / s);
    float pv = val * vbuf[c];
    pv += __shfl_xor(pv, 8);
    pv += __shfl_xor(pv, 4);
    pv += __shfl_xor(pv, 2);
    pv += __shfl_xor(pv, 1);
    if (c == 0) pbuf[node] = pv;
}

// ---------------- pooling: out[g] += r[n] + c0 ----------------
__global__ void pool_kernel(const float* __restrict__ r, const int* __restrict__ batch,
                            const float* __restrict__ vbuf, float* __restrict__ out,
                            int N) {
    int i = blockIdx.x * blockDim.x + threadIdx.x;
    if (i < N) atomicAdd(&out[batch[i]], r[i] + vbuf[16]);
}

// ---------------- launcher ----------------

extern "C" void kernel_launch(void* const* d_in, const int* in_sizes, int n_in,
                              void* d_out, int out_size, void* d_ws, size_t ws_size,
                              hipStream_t stream) {
    const float* x = (const float*)d_in[0];
    const int* edge_index = (const int*)d_in[1];
    const int* batch = (const int*)d_in[2];
    const float* lin1_w = (const float*)d_in[4];
    const float* lin1_b = (const float*)d_in[5];
    const float* beta1 = (const float*)d_in[6];
    const float* beta2 = (const float*)d_in[7];
    const float* lin2_w = (const float*)d_in[8];
    const float* lin2_b = (const float*)d_in[9];
    const float* gather_w = (const float*)d_in[10];
    const float* gather_b = (const float*)d_in[11];
    float* out = (float*)d_out;

    const int N = in_sizes[2];
    const int E = in_sizes[1] / 2;
    const int D = in_sizes[0] / N;  // 75
    const int G = out_size;
    const int NB = (N + NPB - 1) >> NPB_SHIFT;  // 256 buckets

    const int* src = edge_index;
    const int* dst = edge_index + E;

    // workspace carve (4-byte units). The packed edge buffer (E ints) aliases
    // the float/fp16 feature region, which is written only after csr_build.
    float* w = (float*)d_ws;
    int* packed = (int*)d_ws;            // E ints, alias
    __half* xn1h = (__half*)w;           w += (size_t)N * 8;   // N*16 halves
    __half* xn2h = (__half*)w;           w += (size_t)N * 8;
    float* s1 = w;                       w += N;
    float* out1 = w;                     w += (size_t)N * 16;
    float* pbuf = w;                     w += N;
    float* rbuf = w;                     w += N;
    float* vbuf = w;                     w += 32;
    int* deg = (int*)w;                  w += N;
    int* offs = (int*)w;                 w += N;
    int* csr_src = (int*)w;              w += E;
    int* gcount = (int*)w;               w += MAXB;
    int* gbase = (int*)w;                w += MAXB + 1;
    int* gcursor = (int*)w;              w += MAXB;

    const int B = 256;
    dim3 gridNode16((N + (B / 16) - 1) / (B / 16));
    dim3 gridNode8((N + (B / 8) - 1) / (B / 8));
    dim3 gridN((N + B - 1) / B);

    // ---- CSR build (before anything touches the aliased feature region) ----
    zero_ints<<<dim3((MAXB + B - 1) / B), B, 0, stream>>>(gcount, MAXB);
    bucket_count<<<dim3(1024), B, 0, stream>>>(dst, E, gcount, NB);
    bucket_scan<<<dim3(1), MAXB, 0, stream>>>(gcount, gbase, gcursor, NB);
    bucket_scatter<<<dim3((E + B * A2_EPT - 1) / (B * A2_EPT)), B, 0, stream>>>(
        src, dst, E, gcursor, packed, NB);
    csr_build<<<dim3(NB), NPB, 0, stream>>>(packed, gbase, deg, offs, csr_src, N);

    // ---- features ----
    lin1_relu_norm<<<gridNode16, B, 0, stream>>>(x, lin1_w, lin1_b, xn1h, s1, N, D);
    compute_v<<<dim3(1), 64, 0, stream>>>(lin2_w, lin2_b, gather_w, vbuf);

    agnn_conv<true><<<gridNode8, B, 0, stream>>>(xn1h, s1, offs, deg, csr_src,
                                                 beta1, out1, N);
    norm2_proj<<<gridNode16, B, 0, stream>>>(out1, vbuf, xn2h, pbuf, N);
    agnn_conv<false><<<gridNode8, B, 0, stream>>>(xn2h, pbuf, offs, deg, csr_src,
                                                  beta2, rbuf, N);

    init_out<<<dim3((G + B - 1) / B), B, 0, stream>>>(out, gather_b, G);
    pool_kernel<<<gridN, B, 0, stream>>>(rbuf, batch, vbuf, out, N);
}